// Round 11
// baseline (81.058 us; speedup 1.0000x reference)
//
#include <hip/hip_runtime.h>
#include <hip/hip_bf16.h>
#include <stdint.h>

#define T_SEQ 4096
#define CDIM  1024
#define NH    16
#define NKV   4
#define HD    64
#define WIN   512
#define KVD   256      // NKV*HD
#define QKVN  1536     // CDIM + 2*KVD

typedef unsigned short ushort_t;
typedef __attribute__((ext_vector_type(8))) __bf16 bf16x8;
typedef __attribute__((ext_vector_type(4))) float  f32x4;
typedef __attribute__((ext_vector_type(4))) unsigned short us4;

__device__ inline unsigned short f2bf(float f) {
  unsigned u = __builtin_bit_cast(unsigned, f);
  u += 0x7fffu + ((u >> 16) & 1u);
  return (unsigned short)(u >> 16);
}

__device__ inline unsigned cvt_pk_bf16(float lo, float hi) {
  unsigned r;
  asm("v_cvt_pk_bf16_f32 %0, %1, %2" : "=v"(r) : "v"(lo), "v"(hi));
  return r;
}

__device__ inline f32x4 mfma16(bf16x8 a, bf16x8 b, f32x4 c) {
  return __builtin_amdgcn_mfma_f32_16x16x32_bf16(a, b, c, 0, 0, 0);
}

__device__ inline void load_lds16(const void* g, void* s) {
  __builtin_amdgcn_global_load_lds(
      (const __attribute__((address_space(1))) void*)g,
      (__attribute__((address_space(3))) void*)s, 16, 0, 0);
}

// ---------------- prep: f32 -> bf16 conversions + rope tables ----------------
__global__ __launch_bounds__(256) void prep_kernel(
    const float* __restrict__ x,  const float* __restrict__ wq,
    const float* __restrict__ wk, const float* __restrict__ wv,
    const float* __restrict__ wo,
    ushort_t* __restrict__ xb, ushort_t* __restrict__ wqkvb,
    ushort_t* __restrict__ wob,
    float* __restrict__ ct, float* __restrict__ st) {
  const int NX  = T_SEQ * CDIM / 4;   // 1048576 vec4s
  const int NWQ = CDIM * CDIM / 4;    // 262144
  const int NWK = KVD * CDIM / 4;     // 65536
  const int NCONV = NX + 2 * NWQ + 2 * NWK;
  int i = blockIdx.x * 256 + threadIdx.x;
  if (i >= NCONV) {
    int j = i - NCONV;
    if (j >= T_SEQ * 32) return;
    int t = j >> 5, f = j & 31;
    float inv = __builtin_exp2f(-(float)f * (13.287712379549449f / 32.0f));
    float a = (float)t * inv;
    ct[j] = cosf(a);
    st[j] = sinf(a);
    return;
  }
  const float4* src; ushort_t* dst; int off;
  if (i < NX)                        { src = (const float4*)x;  dst = xb;                              off = i; }
  else if (i < NX + NWQ)             { src = (const float4*)wq; dst = wqkvb;                           off = i - NX; }
  else if (i < NX + NWQ + NWK)       { src = (const float4*)wk; dst = wqkvb + CDIM * CDIM;             off = i - NX - NWQ; }
  else if (i < NX + NWQ + 2 * NWK)   { src = (const float4*)wv; dst = wqkvb + CDIM * CDIM + KVD * CDIM; off = i - NX - NWQ - NWK; }
  else                               { src = (const float4*)wo; dst = wob;                             off = i - NX - NWQ - 2 * NWK; }
  float4 v = src[off];
  us4 o; o.x = f2bf(v.x); o.y = f2bf(v.y); o.z = f2bf(v.z); o.w = f2bf(v.w);
  *(us4*)(dst + (size_t)off * 4) = o;
}

// ---------------- GEMM: C = A(MxK) * B(NxK)^T, bf16 in, f32 acc ----------------
// BM=64, BN=64, BK=64 (occupancy-driven: 32KB LDS -> 4-5 blocks/CU).
// EPI=0 (QKV): waves 4x1, wave-tile 16x64 (keeps RoPE pairs d/d+32 in-lane).
// EPI=1 (out): waves 2x2, wave-tile 32x32.
// 2-phase double-buffered K-loop (counted vmcnt), XCD block swizzle,
// XOR chunk-swizzled LDS (stride-128B rows).
template <int EPI>
__global__ __launch_bounds__(256) void gemm_kernel(
    const ushort_t* __restrict__ A, const ushort_t* __restrict__ B, int K,
    float* __restrict__ outF,
    ushort_t* __restrict__ qbuf, ushort_t* __restrict__ kbuf, ushort_t* __restrict__ vt,
    const float* __restrict__ ct, const float* __restrict__ st) {
  __shared__ __align__(16) ushort_t smA[2][64 * 64];
  __shared__ __align__(16) ushort_t smB[2][64 * 64];
  const int tid = threadIdx.x, lane = tid & 63, wid = tid >> 6;

  // XCD-aware swizzle: nwg (1536 / 1024) divisible by 8; gridDim.x == 64.
  const int id = blockIdx.x + (gridDim.x * blockIdx.y);
  const int nwg = gridDim.x * gridDim.y;
  const int swz = (id & 7) * (nwg >> 3) + (id >> 3);
  const int bm = (swz & 63) * 64, bn = (swz >> 6) * 64;

  const int wr = wid >> 1, wc = wid & 1;   // EPI=1 tiling
  const int l15 = lane & 15, lg = lane >> 4;
  const int r8 = lane >> 3;          // row within staging inst (8 rows x 128B)
  const int cc = lane & 7;           // dest 16B chunk within row
  const int scc = (cc ^ r8) * 8;     // swizzled source elem offset

  f32x4 acc[4];
#pragma unroll
  for (int j = 0; j < 4; j++) acc[j] = (f32x4)0.0f;

#define GSTAGE(buf, ktv)                                                                          \
  do {                                                                                            \
    load_lds16(A + (size_t)(bm + wid * 8 + r8) * K + (ktv) + scc, (char*)smA[buf] + wid * 1024);             \
    load_lds16(A + (size_t)(bm + (wid + 4) * 8 + r8) * K + (ktv) + scc, (char*)smA[buf] + (wid + 4) * 1024); \
    load_lds16(B + (size_t)(bn + wid * 8 + r8) * K + (ktv) + scc, (char*)smB[buf] + wid * 1024);             \
    load_lds16(B + (size_t)(bn + (wid + 4) * 8 + r8) * K + (ktv) + scc, (char*)smB[buf] + (wid + 4) * 1024); \
  } while (0)

  GSTAGE(0, 0);
  const int NK = K / 64;
  int cur = 0;
  for (int kt = 0; kt < NK; ++kt) {
    if (kt + 1 < NK) {
      GSTAGE(cur ^ 1, (kt + 1) * 64);
      asm volatile("s_waitcnt vmcnt(4)" ::: "memory");  // own cur-tile loads landed
    } else {
      asm volatile("s_waitcnt vmcnt(0)" ::: "memory");
    }
    __builtin_amdgcn_sched_barrier(0);
    __builtin_amdgcn_s_barrier();      // everyone's cur-tile loads landed
    __builtin_amdgcn_sched_barrier(0);

    if (EPI == 0) {
      // wave-tile 16x64: one M-frag (rows wid*16..+16), 4 N-frags
      const int ra_ = wid * 16 + l15, swa = ra_ & 7;
      bf16x8 af[2];
#pragma unroll
      for (int ks = 0; ks < 2; ks++)
        af[ks] = *(const bf16x8*)&smA[cur][ra_ * 64 + ((ks * 4 + lg) ^ swa) * 8];
#pragma unroll
      for (int ni = 0; ni < 4; ni++) {
        const int rb_ = ni * 16 + l15, swb = rb_ & 7;
#pragma unroll
        for (int ks = 0; ks < 2; ks++) {
          bf16x8 bfr = *(const bf16x8*)&smB[cur][rb_ * 64 + ((ks * 4 + lg) ^ swb) * 8];
          acc[ni] = mfma16(af[ks], bfr, acc[ni]);
        }
      }
    } else {
      // wave-tile 32x32: 2 M-frags x 2 N-frags
      bf16x8 af[2][2], bfr[2][2];
#pragma unroll
      for (int mi = 0; mi < 2; mi++) {
        const int r = wr * 32 + mi * 16 + l15, sw8 = r & 7;
#pragma unroll
        for (int ks = 0; ks < 2; ks++)
          af[mi][ks] = *(const bf16x8*)&smA[cur][r * 64 + ((ks * 4 + lg) ^ sw8) * 8];
      }
#pragma unroll
      for (int ni = 0; ni < 2; ni++) {
        const int r = wc * 32 + ni * 16 + l15, sw8 = r & 7;
#pragma unroll
        for (int ks = 0; ks < 2; ks++)
          bfr[ni][ks] = *(const bf16x8*)&smB[cur][r * 64 + ((ks * 4 + lg) ^ sw8) * 8];
      }
#pragma unroll
      for (int ks = 0; ks < 2; ks++)
#pragma unroll
        for (int mi = 0; mi < 2; mi++)
#pragma unroll
          for (int ni = 0; ni < 2; ni++)
            acc[mi * 2 + ni] = mfma16(af[mi][ks], bfr[ni][ks], acc[mi * 2 + ni]);
    }

    __builtin_amdgcn_sched_barrier(0);
    __builtin_amdgcn_s_barrier();      // all reads of cur done before restage
    __builtin_amdgcn_sched_barrier(0);
    cur ^= 1;
  }
#undef GSTAGE

  if (EPI == 1) {
#pragma unroll
    for (int mi = 0; mi < 2; mi++) {
      int r0 = bm + wr * 32 + mi * 16 + lg * 4;
#pragma unroll
      for (int ni = 0; ni < 2; ni++) {
        int c = bn + wc * 32 + ni * 16 + l15;
#pragma unroll
        for (int r = 0; r < 4; r++) outF[(size_t)(r0 + r) * CDIM + c] = acc[mi * 2 + ni][r];
      }
    }
  } else {
    const int t0 = bm + wid * 16 + lg * 4;
    if (bn < CDIM + KVD) {
      // Q or K: apply rope. pairs (dd, dd+32) are frags ni and ni+2, same lane.
      bool isQ = (bn < CDIM);
      ushort_t* obuf = isQ ? qbuf : kbuf;
      int ostride = isQ ? CDIM : KVD;
      int obase = isQ ? bn : bn - CDIM;
#pragma unroll
      for (int ni = 0; ni < 2; ni++) {
        int dd = ni * 16 + l15;  // 0..31 within head
#pragma unroll
        for (int r = 0; r < 4; r++) {
          int t = t0 + r;
          float c_ = ct[t * 32 + dd], s_ = st[t * 32 + dd];
          float lo = acc[ni][r], hi = acc[ni + 2][r];
          obuf[(size_t)t * ostride + obase + dd]      = f2bf(lo * c_ - hi * s_);
          obuf[(size_t)t * ostride + obase + dd + 32] = f2bf(hi * c_ + lo * s_);
        }
      }
    } else {
      // V: transpose to vt[cv][T]
#pragma unroll
      for (int ni = 0; ni < 4; ni++) {
        int cv = bn + ni * 16 + l15 - (CDIM + KVD);  // 0..255
        us4 o;
        o.x = f2bf(acc[ni][0]); o.y = f2bf(acc[ni][1]);
        o.z = f2bf(acc[ni][2]); o.w = f2bf(acc[ni][3]);
        *(us4*)&vt[(size_t)cv * T_SEQ + t0] = o;
      }
    }
  }
}

// ---------------- flash attention, sliding window ----------------
// Block = 64 queries of one head, 4 waves x 16 queries. Grid 1024 = 4 blocks/CU.
// NO-MAX softmax (linear); in-register P relayout via permlane swaps.
__global__ __launch_bounds__(256, 4) void attn_kernel(
    const ushort_t* __restrict__ qbuf, const ushort_t* __restrict__ kbuf,
    const ushort_t* __restrict__ vt, ushort_t* __restrict__ ybuf) {
  __shared__ __align__(16) ushort_t smK[2][64 * 64];
  __shared__ __align__(16) ushort_t smV[2][64 * 64];
  const int tid = threadIdx.x, lane = tid & 63, wid = tid >> 6;
  const int l15 = lane & 15, lg = lane >> 4;
  const int blk = blockIdx.x;
  // XCD-aware head/q decomposition (bijective over 1024 blocks):
  const int h  = (blk & 7) * 2 + ((blk >> 3) & 1);
  const int qb = (blk >> 4) * 64;    // block query base
  const int kvh = h >> 2;            // n_rep = 4
  const int qbw = qb + wid * 16;     // wave query base (16 queries)

  const int r8 = lane >> 3;          // 0..7 row within staging inst
  const int cc = lane & 7;           // dest 16B chunk within row
  const int sc = ((cc ^ r8) * 8);    // swizzled source elem offset
  const int ra = wid * 8 + r8;
  const int rb = (wid + 4) * 8 + r8;

  int kb0 = qb - (WIN - 1);
  if (kb0 < 0) kb0 = 0;
  kb0 &= ~63;
  const int nt = ((qb + 63) - kb0) / 64 + 1;

#define STAGE(buf, kbase)                                                                  \
  do {                                                                                     \
    load_lds16(kbuf + (size_t)((kbase) + ra) * KVD + kvh * HD + sc, (char*)smK[buf] + wid * 1024);        \
    load_lds16(kbuf + (size_t)((kbase) + rb) * KVD + kvh * HD + sc, (char*)smK[buf] + (wid + 4) * 1024);  \
    load_lds16(vt + (size_t)(kvh * HD + ra) * T_SEQ + (kbase) + sc, (char*)smV[buf] + wid * 1024);        \
    load_lds16(vt + (size_t)(kvh * HD + rb) * T_SEQ + (kbase) + sc, (char*)smV[buf] + (wid + 4) * 1024);  \
  } while (0)

  STAGE(0, kb0);

  // Q fragments: [d-half]
  const ushort_t* qrow = qbuf + (size_t)(qbw + l15) * CDIM + h * HD;
  bf16x8 qf0 = *(const bf16x8*)(qrow + lg * 8);
  bf16x8 qf1 = *(const bf16x8*)(qrow + 32 + lg * 8);

  f32x4 o[4];
#pragma unroll
  for (int j = 0; j < 4; j++) o[j] = (f32x4)0.f;
  float lpart = 0.f;                // per-lane partial sum of p (reduced at end)
  const float SC = 0.125f * 1.4426950408889634f;  // scale * log2(e)
  const int sw = l15 & 7;           // K/V LDS read chunk swizzle

  int cur = 0;
  for (int t = 0; t < nt; ++t) {
    const int kb = kb0 + t * 64;
    if (t + 1 < nt) {
      STAGE(cur ^ 1, kb + 64);
      asm volatile("s_waitcnt vmcnt(4)" ::: "memory");
    } else {
      asm volatile("s_waitcnt vmcnt(0)" ::: "memory");
    }
    __builtin_amdgcn_sched_barrier(0);
    __builtin_amdgcn_s_barrier();
    __builtin_amdgcn_sched_barrier(0);

    if (kb <= qbw + 15) {  // wave-uniform skip of tiles above diagonal
      const ushort_t* sk = smK[cur];
      const ushort_t* sv_ = smV[cur];

      // ---- QK^T: S^T[k][q], 4 key groups of 16 ----
      f32x4 s[4];
      __builtin_amdgcn_s_setprio(1);
#pragma unroll
      for (int g = 0; g < 4; g++) {
        bf16x8 k0 = *(const bf16x8*)&sk[(g * 16 + l15) * 64 + ((lg ^ sw) * 8)];
        bf16x8 k1 = *(const bf16x8*)&sk[(g * 16 + l15) * 64 + (((4 + lg) ^ sw) * 8)];
        s[g] = mfma16(k0, qf0, (f32x4)0.f);
        s[g] = mfma16(k1, qf1, s[g]);
      }
      __builtin_amdgcn_s_setprio(0);

      // ---- no-max softmax: p = exp2(s*SC) (masked -> 0); pack to bf16 ----
      const bool nomask = (kb + 63 <= qbw) && (kb > qbw + 15 - WIN);
      unsigned pw[8];  // [g*2+m]
      {
        const int q = qbw + l15;
        float ps = 0.f;
#pragma unroll
        for (int g = 0; g < 4; g++) {
          float p0, p1, p2, p3;
          if (nomask) {
            p0 = __builtin_exp2f(s[g][0] * SC);
            p1 = __builtin_exp2f(s[g][1] * SC);
            p2 = __builtin_exp2f(s[g][2] * SC);
            p3 = __builtin_exp2f(s[g][3] * SC);
          } else {
            int k0 = kb + g * 16 + lg * 4;
            p0 = __builtin_exp2f((k0 + 0 <= q && k0 + 0 > q - WIN) ? s[g][0] * SC : -3e38f);
            p1 = __builtin_exp2f((k0 + 1 <= q && k0 + 1 > q - WIN) ? s[g][1] * SC : -3e38f);
            p2 = __builtin_exp2f((k0 + 2 <= q && k0 + 2 > q - WIN) ? s[g][2] * SC : -3e38f);
            p3 = __builtin_exp2f((k0 + 3 <= q && k0 + 3 > q - WIN) ? s[g][3] * SC : -3e38f);
          }
          ps += (p0 + p1) + (p2 + p3);
          pw[g * 2 + 0] = cvt_pk_bf16(p0, p1);
          pw[g * 2 + 1] = cvt_pk_bf16(p2, p3);
        }
        lpart += ps;
      }

      // ---- in-register P^T -> A-operand relayout via permlane swaps ----
      asm("v_permlane32_swap_b32 %0, %1" : "+v"(pw[0]), "+v"(pw[2]));
      asm("v_permlane32_swap_b32 %0, %1" : "+v"(pw[1]), "+v"(pw[3]));
      asm("v_permlane32_swap_b32 %0, %1" : "+v"(pw[4]), "+v"(pw[6]));
      asm("v_permlane32_swap_b32 %0, %1" : "+v"(pw[5]), "+v"(pw[7]));
      asm("v_permlane16_swap_b32 %0, %1" : "+v"(pw[0]), "+v"(pw[2]));
      asm("v_permlane16_swap_b32 %0, %1" : "+v"(pw[1]), "+v"(pw[3]));
      asm("v_permlane16_swap_b32 %0, %1" : "+v"(pw[4]), "+v"(pw[6]));
      asm("v_permlane16_swap_b32 %0, %1" : "+v"(pw[5]), "+v"(pw[7]));
      bf16x8 pf0, pf1;
      {
        union { unsigned u[4]; bf16x8 v; } c0, c1;
        c0.u[0] = pw[0]; c0.u[1] = pw[1]; c0.u[2] = pw[2]; c0.u[3] = pw[3];
        c1.u[0] = pw[4]; c1.u[1] = pw[5]; c1.u[2] = pw[6]; c1.u[3] = pw[7];
        pf0 = c0.v;
        pf1 = c1.v;
      }

      // ---- PV ----
      __builtin_amdgcn_s_setprio(1);
#pragma unroll
      for (int n = 0; n < 4; n++) {
        bf16x8 v0 = *(const bf16x8*)&sv_[(n * 16 + l15) * 64 + ((lg ^ sw) * 8)];
        bf16x8 v1 = *(const bf16x8*)&sv_[(n * 16 + l15) * 64 + (((4 + lg) ^ sw) * 8)];
        o[n] = mfma16(pf0, v0, o[n]);
        o[n] = mfma16(pf1, v1, o[n]);
      }
      __builtin_amdgcn_s_setprio(0);
    }
    __builtin_amdgcn_sched_barrier(0);
    __builtin_amdgcn_s_barrier();  // all waves done reading buf[cur]
    __builtin_amdgcn_sched_barrier(0);
    cur ^= 1;
  }
#undef STAGE

  {
    float l = lpart;
    l += __shfl_xor(l, 16);
    l += __shfl_xor(l, 32);
    float inv = 1.f / l;
    float i0 = __shfl(inv, lg * 4 + 0);
    float i1 = __shfl(inv, lg * 4 + 1);
    float i2 = __shfl(inv, lg * 4 + 2);
    float i3 = __shfl(inv, lg * 4 + 3);
    ushort_t* yb = ybuf + (size_t)qbw * CDIM + h * HD;
#pragma unroll
    for (int r = 0; r < 4; r++) {
      float ir = (r == 0) ? i0 : (r == 1) ? i1 : (r == 2) ? i2 : i3;
      size_t t = lg * 4 + r;
      yb[t * CDIM + 0  + l15] = f2bf(o[0][r] * ir);
      yb[t * CDIM + 16 + l15] = f2bf(o[1][r] * ir);
      yb[t * CDIM + 32 + l15] = f2bf(o[2][r] * ir);
      yb[t * CDIM + 48 + l15] = f2bf(o[3][r] * ir);
    }
  }
}

// ---------------- launch ----------------
extern "C" void kernel_launch(void* const* d_in, const int* in_sizes, int n_in,
                              void* d_out, int out_size, void* d_ws, size_t ws_size,
                              hipStream_t stream) {
  const float* x  = (const float*)d_in[0];
  const float* wq = (const float*)d_in[1];
  const float* wk = (const float*)d_in[2];
  const float* wv = (const float*)d_in[3];
  const float* wo = (const float*)d_in[4];
  float* out = (float*)d_out;

  char* ws = (char*)d_ws;
  ushort_t* xb    = (ushort_t*)(ws + 0);          // 8,388,608
  ushort_t* wqkvb = (ushort_t*)(ws + 8388608);    // 3,145,728
  ushort_t* wob   = (ushort_t*)(ws + 11534336);   // 2,097,152
  ushort_t* qbuf  = (ushort_t*)(ws + 13631488);   // 8,388,608
  ushort_t* kbuf  = (ushort_t*)(ws + 22020096);   // 2,097,152
  ushort_t* vt    = (ushort_t*)(ws + 24117248);   // 2,097,152
  ushort_t* ybuf  = (ushort_t*)(ws + 26214400);   // 8,388,608
  float*    ct    = (float*)(ws + 34603008);      // 524,288
  float*    st    = (float*)(ws + 35127296);      // 524,288

  prep_kernel<<<7168, 256, 0, stream>>>(x, wq, wk, wv, wo, xb, wqkvb, wob, ct, st);

  dim3 g1(64, 24);  // M/64 x QKVN/64
  gemm_kernel<0><<<g1, 256, 0, stream>>>(xb, wqkvb, CDIM, nullptr, qbuf, kbuf, vt, ct, st);

  attn_kernel<<<1024, 256, 0, stream>>>(qbuf, kbuf, vt, ybuf);

  dim3 g2(64, 16);  // M/64 x CDIM/64
  gemm_kernel<1><<<g2, 256, 0, stream>>>(ybuf, wob, CDIM, out, nullptr, nullptr, nullptr, nullptr, nullptr);
}

// Round 12
// 72.625 us; speedup vs baseline: 1.1161x; 1.1161x over previous
//
#include <hip/hip_runtime.h>
#include <hip/hip_bf16.h>
#include <stdint.h>

#define T_SEQ 4096
#define CDIM  1024
#define NH    16
#define NKV   4
#define HD    64
#define WIN   512
#define KVD   256      // NKV*HD
#define QKVN  1536     // CDIM + 2*KVD

typedef unsigned short ushort_t;
typedef __attribute__((ext_vector_type(8))) __bf16 bf16x8;
typedef __attribute__((ext_vector_type(4))) float  f32x4;
typedef __attribute__((ext_vector_type(4))) unsigned short us4;
typedef __attribute__((ext_vector_type(8))) unsigned short us8;

__device__ inline unsigned short f2bf(float f) {
  unsigned u = __builtin_bit_cast(unsigned, f);
  u += 0x7fffu + ((u >> 16) & 1u);
  return (unsigned short)(u >> 16);
}

__device__ inline unsigned cvt_pk_bf16(float lo, float hi) {
  unsigned r;
  asm("v_cvt_pk_bf16_f32 %0, %1, %2" : "=v"(r) : "v"(lo), "v"(hi));
  return r;
}

__device__ inline f32x4 mfma16(bf16x8 a, bf16x8 b, f32x4 c) {
  return __builtin_amdgcn_mfma_f32_16x16x32_bf16(a, b, c, 0, 0, 0);
}

__device__ inline void load_lds16(const void* g, void* s) {
  __builtin_amdgcn_global_load_lds(
      (const __attribute__((address_space(1))) void*)g,
      (__attribute__((address_space(3))) void*)s, 16, 0, 0);
}

// ---------------- prep: f32 -> bf16 conversions (32B/thread) + rope tables ----------------
__global__ __launch_bounds__(256) void prep_kernel(
    const float* __restrict__ x,  const float* __restrict__ wq,
    const float* __restrict__ wk, const float* __restrict__ wv,
    const float* __restrict__ wo,
    ushort_t* __restrict__ xb, ushort_t* __restrict__ wqkvb,
    ushort_t* __restrict__ wob,
    float* __restrict__ ct, float* __restrict__ st) {
  const int NX  = T_SEQ * CDIM / 8;   // 524288 pairs of vec4
  const int NWQ = CDIM * CDIM / 8;    // 131072
  const int NWK = KVD * CDIM / 8;     // 32768
  const int NCONV = NX + 2 * NWQ + 2 * NWK;  // 851968 -> 3328 blocks
  int i = blockIdx.x * 256 + threadIdx.x;
  if (i >= NCONV) {
    int j = i - NCONV;
    if (j >= T_SEQ * 32) return;
    int t = j >> 5, f = j & 31;
    float inv = __builtin_exp2f(-(float)f * (13.287712379549449f / 32.0f));
    float a = (float)t * inv;
    ct[j] = cosf(a);
    st[j] = sinf(a);
    return;
  }
  const float4* src; ushort_t* dst; int off;
  if (i < NX)                        { src = (const float4*)x;  dst = xb;                              off = i; }
  else if (i < NX + NWQ)             { src = (const float4*)wq; dst = wqkvb;                           off = i - NX; }
  else if (i < NX + NWQ + NWK)       { src = (const float4*)wk; dst = wqkvb + CDIM * CDIM;             off = i - NX - NWQ; }
  else if (i < NX + NWQ + 2 * NWK)   { src = (const float4*)wv; dst = wqkvb + CDIM * CDIM + KVD * CDIM; off = i - NX - NWQ - NWK; }
  else                               { src = (const float4*)wo; dst = wob;                             off = i - NX - NWQ - 2 * NWK; }
  float4 v0 = src[off * 2], v1 = src[off * 2 + 1];
  us8 o;
  o[0] = f2bf(v0.x); o[1] = f2bf(v0.y); o[2] = f2bf(v0.z); o[3] = f2bf(v0.w);
  o[4] = f2bf(v1.x); o[5] = f2bf(v1.y); o[6] = f2bf(v1.z); o[7] = f2bf(v1.w);
  *(us8*)(dst + (size_t)off * 8) = o;
}

// ---------------- GEMM: C = A(MxK) * B(NxK)^T, bf16 in, f32 acc ----------------
// BM=64, BN=128, BK=64. 4 waves 2x2, wave-tile 32x64, acc[2][4].
// 2-phase double-buffered K-loop (counted vmcnt), XCD block swizzle, and
// XOR chunk-swizzled LDS (row stride 128B would otherwise be a 32-way
// bank conflict; swizzle applied on global source, m173 pattern).
template <int EPI>
__global__ __launch_bounds__(256) void gemm_kernel(
    const ushort_t* __restrict__ A, const ushort_t* __restrict__ B, int K,
    float* __restrict__ outF,
    ushort_t* __restrict__ qbuf, ushort_t* __restrict__ kbuf, ushort_t* __restrict__ vt,
    const float* __restrict__ ct, const float* __restrict__ st) {
  __shared__ __align__(16) ushort_t smA[2][64 * 64];
  __shared__ __align__(16) ushort_t smB[2][128 * 64];
  const int tid = threadIdx.x, lane = tid & 63, wid = tid >> 6;

  // XCD-aware swizzle: nwg divisible by 8 for both launches; gridDim.x == 64.
  const int id = blockIdx.x + (gridDim.x * blockIdx.y);
  const int nwg = gridDim.x * gridDim.y;
  const int swz = (id & 7) * (nwg >> 3) + (id >> 3);
  const int bm = (swz & 63) * 64, bn = (swz >> 6) * 128;

  const int wr = wid >> 1, wc = wid & 1;
  const int l15 = lane & 15, lg = lane >> 4;
  const int r8 = lane >> 3;          // row within staging inst (8 rows x 128B)
  const int cc = lane & 7;           // dest 16B chunk within row
  const int scc = (cc ^ r8) * 8;     // swizzled source elem offset

  f32x4 acc[2][4];
#pragma unroll
  for (int i = 0; i < 2; i++)
#pragma unroll
    for (int j = 0; j < 4; j++) acc[i][j] = (f32x4)0.0f;

#define GSTAGE(buf, ktv)                                                                              \
  do {                                                                                                \
    load_lds16(A + (size_t)(bm + wid * 8 + r8) * K + (ktv) + scc, (char*)smA[buf] + wid * 1024);                 \
    load_lds16(A + (size_t)(bm + (wid + 4) * 8 + r8) * K + (ktv) + scc, (char*)smA[buf] + (wid + 4) * 1024);     \
    load_lds16(B + (size_t)(bn + wid * 8 + r8) * K + (ktv) + scc, (char*)smB[buf] + wid * 1024);                 \
    load_lds16(B + (size_t)(bn + (wid + 4) * 8 + r8) * K + (ktv) + scc, (char*)smB[buf] + (wid + 4) * 1024);     \
    load_lds16(B + (size_t)(bn + (wid + 8) * 8 + r8) * K + (ktv) + scc, (char*)smB[buf] + (wid + 8) * 1024);     \
    load_lds16(B + (size_t)(bn + (wid + 12) * 8 + r8) * K + (ktv) + scc, (char*)smB[buf] + (wid + 12) * 1024);   \
  } while (0)

  GSTAGE(0, 0);
  const int NK = K / 64;
  int cur = 0;
  for (int kt = 0; kt < NK; ++kt) {
    if (kt + 1 < NK) {
      GSTAGE(cur ^ 1, (kt + 1) * 64);
      asm volatile("s_waitcnt vmcnt(6)" ::: "memory");  // own cur-tile loads landed
    } else {
      asm volatile("s_waitcnt vmcnt(0)" ::: "memory");
    }
    __builtin_amdgcn_sched_barrier(0);
    __builtin_amdgcn_s_barrier();      // everyone's cur-tile loads landed
    __builtin_amdgcn_sched_barrier(0);

    bf16x8 af[2][2], bfr[4][2];
#pragma unroll
    for (int mi = 0; mi < 2; mi++) {
      int r = wr * 32 + mi * 16 + l15, sw8 = r & 7;
#pragma unroll
      for (int ks = 0; ks < 2; ks++)
        af[mi][ks] = *(const bf16x8*)&smA[cur][r * 64 + ((ks * 4 + lg) ^ sw8) * 8];
    }
#pragma unroll
    for (int ni = 0; ni < 4; ni++) {
      int r = wc * 64 + ni * 16 + l15, sw8 = r & 7;
#pragma unroll
      for (int ks = 0; ks < 2; ks++)
        bfr[ni][ks] = *(const bf16x8*)&smB[cur][r * 64 + ((ks * 4 + lg) ^ sw8) * 8];
    }
#pragma unroll
    for (int ks = 0; ks < 2; ks++)
#pragma unroll
      for (int mi = 0; mi < 2; mi++)
#pragma unroll
        for (int ni = 0; ni < 4; ni++)
          acc[mi][ni] = mfma16(af[mi][ks], bfr[ni][ks], acc[mi][ni]);

    __builtin_amdgcn_sched_barrier(0);
    __builtin_amdgcn_s_barrier();      // all reads of cur done before restage
    __builtin_amdgcn_sched_barrier(0);
    cur ^= 1;
  }
#undef GSTAGE

  const int col0 = bn + wc * 64;  // wave's 64-col span
  if (EPI == 1) {
#pragma unroll
    for (int mi = 0; mi < 2; mi++) {
      int r0 = bm + wr * 32 + mi * 16 + lg * 4;
#pragma unroll
      for (int ni = 0; ni < 4; ni++) {
        int c = col0 + ni * 16 + l15;
#pragma unroll
        for (int r = 0; r < 4; r++) outF[(size_t)(r0 + r) * CDIM + c] = acc[mi][ni][r];
      }
    }
  } else {
    if (col0 < CDIM + KVD) {
      bool isQ = (col0 < CDIM);
      ushort_t* obuf = isQ ? qbuf : kbuf;
      int ostride = isQ ? CDIM : KVD;
      int obase = isQ ? col0 : col0 - CDIM;
#pragma unroll
      for (int mi = 0; mi < 2; mi++) {
        int r0 = bm + wr * 32 + mi * 16 + lg * 4;
#pragma unroll
        for (int ni = 0; ni < 2; ni++) {
          int dd = ni * 16 + l15;  // 0..31 within head
#pragma unroll
          for (int r = 0; r < 4; r++) {
            int t = r0 + r;
            float c_ = ct[t * 32 + dd], s_ = st[t * 32 + dd];
            float lo = acc[mi][ni][r], hi = acc[mi][ni + 2][r];
            obuf[(size_t)t * ostride + obase + dd]      = f2bf(lo * c_ - hi * s_);
            obuf[(size_t)t * ostride + obase + dd + 32] = f2bf(hi * c_ + lo * s_);
          }
        }
      }
    } else {
#pragma unroll
      for (int mi = 0; mi < 2; mi++) {
        int t0 = bm + wr * 32 + mi * 16 + lg * 4;
#pragma unroll
        for (int ni = 0; ni < 4; ni++) {
          int cv = col0 + ni * 16 + l15 - (CDIM + KVD);  // 0..255
          us4 o;
          o.x = f2bf(acc[mi][ni][0]); o.y = f2bf(acc[mi][ni][1]);
          o.z = f2bf(acc[mi][ni][2]); o.w = f2bf(acc[mi][ni][3]);
          *(us4*)&vt[(size_t)cv * T_SEQ + t0] = o;
        }
      }
    }
  }
}

// ---------------- flash attention, sliding window ----------------
// Block = 64 queries of one head, 4 waves x 16 queries. Grid 1024 = 4 blocks/CU.
// NO-MAX softmax (linear); in-register P relayout via permlane swaps.
__global__ __launch_bounds__(256, 4) void attn_kernel(
    const ushort_t* __restrict__ qbuf, const ushort_t* __restrict__ kbuf,
    const ushort_t* __restrict__ vt, ushort_t* __restrict__ ybuf) {
  __shared__ __align__(16) ushort_t smK[2][64 * 64];
  __shared__ __align__(16) ushort_t smV[2][64 * 64];
  const int tid = threadIdx.x, lane = tid & 63, wid = tid >> 6;
  const int l15 = lane & 15, lg = lane >> 4;
  const int blk = blockIdx.x;
  // XCD-aware head/q decomposition (bijective over 1024 blocks):
  const int h  = (blk & 7) * 2 + ((blk >> 3) & 1);
  const int qb = (blk >> 4) * 64;    // block query base
  const int kvh = h >> 2;            // n_rep = 4
  const int qbw = qb + wid * 16;     // wave query base (16 queries)

  const int r8 = lane >> 3;          // 0..7 row within staging inst
  const int cc = lane & 7;           // dest 16B chunk within row
  const int sc = ((cc ^ r8) * 8);    // swizzled source elem offset
  const int ra = wid * 8 + r8;
  const int rb = (wid + 4) * 8 + r8;

  int kb0 = qb - (WIN - 1);
  if (kb0 < 0) kb0 = 0;
  kb0 &= ~63;
  const int nt = ((qb + 63) - kb0) / 64 + 1;

#define STAGE(buf, kbase)                                                                  \
  do {                                                                                     \
    load_lds16(kbuf + (size_t)((kbase) + ra) * KVD + kvh * HD + sc, (char*)smK[buf] + wid * 1024);        \
    load_lds16(kbuf + (size_t)((kbase) + rb) * KVD + kvh * HD + sc, (char*)smK[buf] + (wid + 4) * 1024);  \
    load_lds16(vt + (size_t)(kvh * HD + ra) * T_SEQ + (kbase) + sc, (char*)smV[buf] + wid * 1024);        \
    load_lds16(vt + (size_t)(kvh * HD + rb) * T_SEQ + (kbase) + sc, (char*)smV[buf] + (wid + 4) * 1024);  \
  } while (0)

  STAGE(0, kb0);

  // Q fragments: [d-half]
  const ushort_t* qrow = qbuf + (size_t)(qbw + l15) * CDIM + h * HD;
  bf16x8 qf0 = *(const bf16x8*)(qrow + lg * 8);
  bf16x8 qf1 = *(const bf16x8*)(qrow + 32 + lg * 8);

  f32x4 o[4];
#pragma unroll
  for (int j = 0; j < 4; j++) o[j] = (f32x4)0.f;
  float lpart = 0.f;                // per-lane partial sum of p (reduced at end)
  const float SC = 0.125f * 1.4426950408889634f;  // scale * log2(e)
  const int sw = l15 & 7;           // K/V LDS read chunk swizzle

  int cur = 0;
  for (int t = 0; t < nt; ++t) {
    const int kb = kb0 + t * 64;
    if (t + 1 < nt) {
      STAGE(cur ^ 1, kb + 64);
      asm volatile("s_waitcnt vmcnt(4)" ::: "memory");
    } else {
      asm volatile("s_waitcnt vmcnt(0)" ::: "memory");
    }
    __builtin_amdgcn_sched_barrier(0);
    __builtin_amdgcn_s_barrier();
    __builtin_amdgcn_sched_barrier(0);

    if (kb <= qbw + 15) {  // wave-uniform skip of tiles above diagonal
      const ushort_t* sk = smK[cur];
      const ushort_t* sv_ = smV[cur];

      // ---- QK^T: S^T[k][q], 4 key groups of 16 ----
      f32x4 s[4];
      __builtin_amdgcn_s_setprio(1);
#pragma unroll
      for (int g = 0; g < 4; g++) {
        bf16x8 k0 = *(const bf16x8*)&sk[(g * 16 + l15) * 64 + ((lg ^ sw) * 8)];
        bf16x8 k1 = *(const bf16x8*)&sk[(g * 16 + l15) * 64 + (((4 + lg) ^ sw) * 8)];
        s[g] = mfma16(k0, qf0, (f32x4)0.f);
        s[g] = mfma16(k1, qf1, s[g]);
      }
      __builtin_amdgcn_s_setprio(0);

      // ---- no-max softmax: p = exp2(s*SC) (masked -> 0); pack to bf16 ----
      const bool nomask = (kb + 63 <= qbw) && (kb > qbw + 15 - WIN);
      unsigned pw[8];  // [g*2+m]
      {
        const int q = qbw + l15;
        float ps = 0.f;
#pragma unroll
        for (int g = 0; g < 4; g++) {
          float p0, p1, p2, p3;
          if (nomask) {
            p0 = __builtin_exp2f(s[g][0] * SC);
            p1 = __builtin_exp2f(s[g][1] * SC);
            p2 = __builtin_exp2f(s[g][2] * SC);
            p3 = __builtin_exp2f(s[g][3] * SC);
          } else {
            int k0 = kb + g * 16 + lg * 4;
            p0 = __builtin_exp2f((k0 + 0 <= q && k0 + 0 > q - WIN) ? s[g][0] * SC : -3e38f);
            p1 = __builtin_exp2f((k0 + 1 <= q && k0 + 1 > q - WIN) ? s[g][1] * SC : -3e38f);
            p2 = __builtin_exp2f((k0 + 2 <= q && k0 + 2 > q - WIN) ? s[g][2] * SC : -3e38f);
            p3 = __builtin_exp2f((k0 + 3 <= q && k0 + 3 > q - WIN) ? s[g][3] * SC : -3e38f);
          }
          ps += (p0 + p1) + (p2 + p3);
          pw[g * 2 + 0] = cvt_pk_bf16(p0, p1);
          pw[g * 2 + 1] = cvt_pk_bf16(p2, p3);
        }
        lpart += ps;
      }

      // ---- in-register P^T -> A-operand relayout via permlane swaps ----
      asm("v_permlane32_swap_b32 %0, %1" : "+v"(pw[0]), "+v"(pw[2]));
      asm("v_permlane32_swap_b32 %0, %1" : "+v"(pw[1]), "+v"(pw[3]));
      asm("v_permlane32_swap_b32 %0, %1" : "+v"(pw[4]), "+v"(pw[6]));
      asm("v_permlane32_swap_b32 %0, %1" : "+v"(pw[5]), "+v"(pw[7]));
      asm("v_permlane16_swap_b32 %0, %1" : "+v"(pw[0]), "+v"(pw[2]));
      asm("v_permlane16_swap_b32 %0, %1" : "+v"(pw[1]), "+v"(pw[3]));
      asm("v_permlane16_swap_b32 %0, %1" : "+v"(pw[4]), "+v"(pw[6]));
      asm("v_permlane16_swap_b32 %0, %1" : "+v"(pw[5]), "+v"(pw[7]));
      bf16x8 pf0, pf1;
      {
        union { unsigned u[4]; bf16x8 v; } c0, c1;
        c0.u[0] = pw[0]; c0.u[1] = pw[1]; c0.u[2] = pw[2]; c0.u[3] = pw[3];
        c1.u[0] = pw[4]; c1.u[1] = pw[5]; c1.u[2] = pw[6]; c1.u[3] = pw[7];
        pf0 = c0.v;
        pf1 = c1.v;
      }

      // ---- PV ----
      __builtin_amdgcn_s_setprio(1);
#pragma unroll
      for (int n = 0; n < 4; n++) {
        bf16x8 v0 = *(const bf16x8*)&sv_[(n * 16 + l15) * 64 + ((lg ^ sw) * 8)];
        bf16x8 v1 = *(const bf16x8*)&sv_[(n * 16 + l15) * 64 + (((4 + lg) ^ sw) * 8)];
        o[n] = mfma16(pf0, v0, o[n]);
        o[n] = mfma16(pf1, v1, o[n]);
      }
      __builtin_amdgcn_s_setprio(0);
    }
    __builtin_amdgcn_sched_barrier(0);
    __builtin_amdgcn_s_barrier();  // all waves done reading buf[cur]
    __builtin_amdgcn_sched_barrier(0);
    cur ^= 1;
  }
#undef STAGE

  {
    float l = lpart;
    l += __shfl_xor(l, 16);
    l += __shfl_xor(l, 32);
    float inv = 1.f / l;
    float i0 = __shfl(inv, lg * 4 + 0);
    float i1 = __shfl(inv, lg * 4 + 1);
    float i2 = __shfl(inv, lg * 4 + 2);
    float i3 = __shfl(inv, lg * 4 + 3);
    ushort_t* yb = ybuf + (size_t)qbw * CDIM + h * HD;
#pragma unroll
    for (int r = 0; r < 4; r++) {
      float ir = (r == 0) ? i0 : (r == 1) ? i1 : (r == 2) ? i2 : i3;
      size_t t = lg * 4 + r;
      yb[t * CDIM + 0  + l15] = f2bf(o[0][r] * ir);
      yb[t * CDIM + 16 + l15] = f2bf(o[1][r] * ir);
      yb[t * CDIM + 32 + l15] = f2bf(o[2][r] * ir);
      yb[t * CDIM + 48 + l15] = f2bf(o[3][r] * ir);
    }
  }
}

// ---------------- launch ----------------
extern "C" void kernel_launch(void* const* d_in, const int* in_sizes, int n_in,
                              void* d_out, int out_size, void* d_ws, size_t ws_size,
                              hipStream_t stream) {
  const float* x  = (const float*)d_in[0];
  const float* wq = (const float*)d_in[1];
  const float* wk = (const float*)d_in[2];
  const float* wv = (const float*)d_in[3];
  const float* wo = (const float*)d_in[4];
  float* out = (float*)d_out;

  char* ws = (char*)d_ws;
  ushort_t* xb    = (ushort_t*)(ws + 0);          // 8,388,608
  ushort_t* wqkvb = (ushort_t*)(ws + 8388608);    // 3,145,728
  ushort_t* wob   = (ushort_t*)(ws + 11534336);   // 2,097,152
  ushort_t* qbuf  = (ushort_t*)(ws + 13631488);   // 8,388,608
  ushort_t* kbuf  = (ushort_t*)(ws + 22020096);   // 2,097,152
  ushort_t* vt    = (ushort_t*)(ws + 24117248);   // 2,097,152
  ushort_t* ybuf  = (ushort_t*)(ws + 26214400);   // 8,388,608
  float*    ct    = (float*)(ws + 34603008);      // 524,288
  float*    st    = (float*)(ws + 35127296);      // 524,288

  prep_kernel<<<3840, 256, 0, stream>>>(x, wq, wk, wv, wo, xb, wqkvb, wob, ct, st);

  dim3 g1(64, 12);  // M/64 x QKVN/128
  gemm_kernel<0><<<g1, 256, 0, stream>>>(xb, wqkvb, CDIM, nullptr, qbuf, kbuf, vt, ct, st);

  attn_kernel<<<1024, 256, 0, stream>>>(qbuf, kbuf, vt, ybuf);

  dim3 g2(64, 8);   // M/64 x CDIM/128
  gemm_kernel<1><<<g2, 256, 0, stream>>>(ybuf, wob, CDIM, out, nullptr, nullptr, nullptr, nullptr, nullptr);
}